// Round 2
// baseline (70.524 us; speedup 1.0000x reference)
//
#include <hip/hip_runtime.h>

// out[b,t,u] = y[b,t]*out[b,t-1,u] + x[b,t]*z[b,t,u], out[b,-1,u]=0
// in layout: [B][T][F] with F=1026: x=col0, y=col1, z=cols 2..1025
// Chunked scan: NC chunks of C timesteps.

#define BB 8
#define TT 4096
#define FF 1026
#define UU 1024
#define CC 128
#define NC 32   // TT / CC

typedef float f2 __attribute__((ext_vector_type(2)));

// ws layout: A[BB*NC] floats, then Bc[BB][NC][UU] floats
// total = (256 + 8*32*1024)*4 bytes ~= 1.001 MiB

__global__ __launch_bounds__(256) void k_partial(const float* __restrict__ in,
                                                 float* __restrict__ A,
                                                 float* __restrict__ Bc) {
    // grid: BB*NC*2 blocks; blockIdx.x = ((b*NC + chunk)<<1) | uslice
    int bid   = blockIdx.x;
    int s     = bid & 1;
    int chunk = (bid >> 1) & (NC - 1);
    int b     = bid >> 6;
    int u     = s * 512 + threadIdx.x * 2;

    const float* row = in + ((size_t)b * TT + (size_t)chunk * CC) * FF;
    float accx = 0.f, accy = 0.f, yprod = 1.f;
#pragma unroll 8
    for (int t = 0; t < CC; ++t) {
        f2 xy = *reinterpret_cast<const f2*>(row + (size_t)t * FF);
        f2 z  = *reinterpret_cast<const f2*>(row + (size_t)t * FF + 2 + u);
        accx  = fmaf(xy.y, accx, xy.x * z.x);
        accy  = fmaf(xy.y, accy, xy.x * z.y);
        yprod *= xy.y;
    }
    f2 o; o.x = accx; o.y = accy;
    *reinterpret_cast<f2*>(Bc + ((size_t)b * NC + chunk) * UU + u) = o;
    if (threadIdx.x == 0 && s == 0) A[b * NC + chunk] = yprod;
}

__global__ __launch_bounds__(256) void k_scan(const float* __restrict__ A,
                                              float* __restrict__ Bc) {
    // one thread per (b, u-pair): BB*UU/2 = 4096 threads -> 16 blocks of 256
    int tid = blockIdx.x * 256 + threadIdx.x;
    int b   = tid / (UU / 2);
    int u   = (tid % (UU / 2)) * 2;
    float cx = 0.f, cy = 0.f;
#pragma unroll
    for (int c = 0; c < NC; ++c) {
        float a = A[b * NC + c];
        f2* p = reinterpret_cast<f2*>(Bc + ((size_t)b * NC + c) * UU + u);
        f2 bv = *p;
        cx = fmaf(a, cx, bv.x);
        cy = fmaf(a, cy, bv.y);
        f2 o; o.x = cx; o.y = cy;
        *p = o;  // Bc[c] now holds carry at END of chunk c
    }
}

__global__ __launch_bounds__(256) void k_final(const float* __restrict__ in,
                                               const float* __restrict__ Bc,
                                               float* __restrict__ out) {
    int bid   = blockIdx.x;
    int s     = bid & 1;
    int chunk = (bid >> 1) & (NC - 1);
    int b     = bid >> 6;
    int u     = s * 512 + threadIdx.x * 2;

    const float* row  = in  + ((size_t)b * TT + (size_t)chunk * CC) * FF;
    float*       orow = out + ((size_t)b * TT + (size_t)chunk * CC) * UU + u;

    float accx = 0.f, accy = 0.f;
    if (chunk != 0) {
        f2 cv = *reinterpret_cast<const f2*>(
            Bc + ((size_t)b * NC + (chunk - 1)) * UU + u);
        accx = cv.x; accy = cv.y;
    }
#pragma unroll 8
    for (int t = 0; t < CC; ++t) {
        f2 xy = *reinterpret_cast<const f2*>(row + (size_t)t * FF);
        f2 z  = *reinterpret_cast<const f2*>(row + (size_t)t * FF + 2 + u);
        accx = fmaf(xy.y, accx, xy.x * z.x);
        accy = fmaf(xy.y, accy, xy.x * z.y);
        f2 o; o.x = accx; o.y = accy;
        __builtin_nontemporal_store(o, reinterpret_cast<f2*>(orow + (size_t)t * UU));
    }
}

extern "C" void kernel_launch(void* const* d_in, const int* in_sizes, int n_in,
                              void* d_out, int out_size, void* d_ws, size_t ws_size,
                              hipStream_t stream) {
    const float* in  = (const float*)d_in[0];
    float*       out = (float*)d_out;
    float*       A   = (float*)d_ws;                 // BB*NC floats
    float*       Bc  = A + BB * NC;                  // BB*NC*UU floats

    k_partial<<<BB * NC * 2, 256, 0, stream>>>(in, A, Bc);
    k_scan<<<(BB * UU / 2) / 256, 256, 0, stream>>>(A, Bc);
    k_final<<<BB * NC * 2, 256, 0, stream>>>(in, Bc, out);
}